// Round 4
// baseline (546.309 us; speedup 1.0000x reference)
//
#include <hip/hip_runtime.h>
#include <hip/hip_bf16.h>
#include <stdint.h>

#define B_ 8
#define M_ 2048
#define N_ 2048
#define D_ 1024

typedef __bf16 bf16x8 __attribute__((ext_vector_type(8)));
typedef float f32x4 __attribute__((ext_vector_type(4)));
typedef uint16_t us4 __attribute__((ext_vector_type(4)));
typedef uint16_t us8 __attribute__((ext_vector_type(8)));

__device__ __forceinline__ uint16_t f2b(float f) {
    uint32_t u = __float_as_uint(f);
    return (uint16_t)((u + 0x7FFFu + ((u >> 16) & 1u)) >> 16);
}
__device__ __forceinline__ float b2f(uint16_t h) {
    return __uint_as_float(((uint32_t)h) << 16);
}

__device__ __forceinline__ void gld16(const uint16_t* g, const uint16_t* l) {
    __builtin_amdgcn_global_load_lds(
        (const __attribute__((address_space(1))) uint32_t*)g,
        (__attribute__((address_space(3))) uint32_t*)l,
        16, 0, 0);
}

// ---------------- split x,y into bf16 hi/lo ----------------
__global__ __launch_bounds__(256) void k_split(const float* __restrict__ x,
                                               const float* __restrict__ y,
                                               uint16_t* __restrict__ xh, uint16_t* __restrict__ xl,
                                               uint16_t* __restrict__ yh, uint16_t* __restrict__ yl) {
    const int i = (blockIdx.x * 256 + threadIdx.x) * 4;
    float4 vx = *(const float4*)(x + i);
    float4 vy = *(const float4*)(y + i);
    float fx[4] = {vx.x, vx.y, vx.z, vx.w};
    float fy[4] = {vy.x, vy.y, vy.z, vy.w};
    us4 hx, lx, hy, ly;
#pragma unroll
    for (int k = 0; k < 4; ++k) {
        uint16_t h = f2b(fx[k]);
        hx[k] = h; lx[k] = f2b(fx[k] - b2f(h));
        uint16_t g = f2b(fy[k]);
        hy[k] = g; ly[k] = f2b(fy[k] - b2f(g));
    }
    *(us4*)(xh + i) = hx;
    *(us4*)(xl + i) = lx;
    *(us4*)(yh + i) = hy;
    *(us4*)(yl + i) = ly;
}

// ---------------- GEMM1: e[b][m][n] = xh.yh^T + xh.yl^T + xl.yh^T ----------------
__global__ __launch_bounds__(256) void k_gemm1(const uint16_t* __restrict__ xh,
                                               const uint16_t* __restrict__ xl,
                                               const uint16_t* __restrict__ yh,
                                               const uint16_t* __restrict__ yl,
                                               float* __restrict__ e) {
    const int b = blockIdx.z;
    const int m0 = blockIdx.x * 128;
    const int n0 = blockIdx.y * 128;
    __shared__ __align__(16) uint16_t lds[16384];  // 4 tiles of 128x32 bf16

    const int tid = threadIdx.x;
    const int lane = tid & 63;
    const int wid = tid >> 6;
    const int wm = (wid & 1) * 64;
    const int wn = (wid >> 1) * 64;
    const int quad = lane >> 4;
    const int r16 = lane & 15;

    const uint16_t* src[4];
    src[0] = xh + ((size_t)b * M_ + m0) * D_;
    src[1] = xl + ((size_t)b * M_ + m0) * D_;
    src[2] = yh + ((size_t)b * N_ + n0) * D_;
    src[3] = yl + ((size_t)b * N_ + n0) * D_;

    f32x4 acc[4][4];
#pragma unroll
    for (int i = 0; i < 4; ++i)
#pragma unroll
        for (int j = 0; j < 4; ++j) acc[i][j] = (f32x4){0.f, 0.f, 0.f, 0.f};

    for (int kt = 0; kt < D_ / 32; ++kt) {
        // async global->LDS staging, width=16: LDS dest = wave-uniform base
        // + lane*16B; per-lane source element (offbase&4095)+lane*8 matches.
#pragma unroll
        for (int c = 0; c < 8; ++c) {
            const int offbase = c * 2048 + wid * 512;   // wave-uniform (elements)
            const int tile = offbase >> 12;
            const int o = (offbase & 4095) + lane * 8;  // element within tile
            const int row = o >> 5;
            const int kk = o & 31;
            gld16(src[tile] + (size_t)row * D_ + kt * 32 + kk, &lds[offbase]);
        }
        __syncthreads();

        bf16x8 ah[4], al[4], bh[4], bl[4];
#pragma unroll
        for (int i = 0; i < 4; ++i) {
            const int ra = (wm + i * 16 + r16) * 32 + quad * 8;
            ah[i] = *(const bf16x8*)&lds[ra];
            al[i] = *(const bf16x8*)&lds[4096 + ra];
            const int rb = (wn + i * 16 + r16) * 32 + quad * 8;
            bh[i] = *(const bf16x8*)&lds[8192 + rb];
            bl[i] = *(const bf16x8*)&lds[12288 + rb];
        }
#pragma unroll
        for (int i = 0; i < 4; ++i)
#pragma unroll
            for (int j = 0; j < 4; ++j) {
                acc[i][j] = __builtin_amdgcn_mfma_f32_16x16x32_bf16(ah[i], bh[j], acc[i][j], 0, 0, 0);
                acc[i][j] = __builtin_amdgcn_mfma_f32_16x16x32_bf16(ah[i], bl[j], acc[i][j], 0, 0, 0);
                acc[i][j] = __builtin_amdgcn_mfma_f32_16x16x32_bf16(al[i], bh[j], acc[i][j], 0, 0, 0);
            }
        __syncthreads();
    }

    float* eb = e + (size_t)b * M_ * N_;
#pragma unroll
    for (int i = 0; i < 4; ++i) {
        const int rbase = m0 + wm + i * 16 + quad * 4;
#pragma unroll
        for (int j = 0; j < 4; ++j) {
            const int col = n0 + wn + j * 16 + r16;
#pragma unroll
            for (int r = 0; r < 4; ++r)
                eb[(size_t)(rbase + r) * N_ + col] = acc[i][j][r];
        }
    }
}

// ---------------- row stats: max and 1/sum(exp) per (b,m) ----------------
__global__ __launch_bounds__(256) void k_rowstats(const float* __restrict__ e,
                                                  float* __restrict__ mx,
                                                  float* __restrict__ inv) {
    const int row = blockIdx.x;  // b_local*M + m
    const float* p = e + (size_t)row * N_;
    const int t = threadIdx.x;
    float4 v0 = ((const float4*)p)[t];
    float4 v1 = ((const float4*)p)[t + 256];
    float m = fmaxf(fmaxf(fmaxf(v0.x, v0.y), fmaxf(v0.z, v0.w)),
                    fmaxf(fmaxf(v1.x, v1.y), fmaxf(v1.z, v1.w)));
#pragma unroll
    for (int s = 32; s > 0; s >>= 1) m = fmaxf(m, __shfl_xor(m, s, 64));
    __shared__ float smax[4];
    __shared__ float ssum[4];
    const int wid = t >> 6, lane = t & 63;
    if (lane == 0) smax[wid] = m;
    __syncthreads();
    m = fmaxf(fmaxf(smax[0], smax[1]), fmaxf(smax[2], smax[3]));
    float s = __expf(v0.x - m) + __expf(v0.y - m) + __expf(v0.z - m) + __expf(v0.w - m)
            + __expf(v1.x - m) + __expf(v1.y - m) + __expf(v1.z - m) + __expf(v1.w - m);
#pragma unroll
    for (int sh = 32; sh > 0; sh >>= 1) s += __shfl_xor(s, sh, 64);
    if (lane == 0) ssum[wid] = s;
    __syncthreads();
    if (t == 0) {
        mx[row] = m;
        inv[row] = 1.0f / (ssum[0] + ssum[1] + ssum[2] + ssum[3]);
    }
}

// ---------------- transposed softmax: pT[b][n][m] = bf16(exp(e[b][m][n]-mx)*inv) ----------------
__global__ __launch_bounds__(256) void k_texp(const float* __restrict__ e,
                                              const float* __restrict__ mx,
                                              const float* __restrict__ inv,
                                              uint16_t* __restrict__ pT) {
    const int b = blockIdx.z, m0 = blockIdx.x * 64, n0 = blockIdx.y * 64;
    __shared__ float tile[64 * 65];
    const int t = threadIdx.x;
    const float* eb = e + (size_t)b * M_ * N_;
#pragma unroll
    for (int q = 0; q < 4; ++q) {
        const int row = q * 16 + (t >> 4);
        const int c4 = (t & 15) * 4;
        float4 v = *(const float4*)&eb[(size_t)(m0 + row) * N_ + n0 + c4];
        const float mv = mx[b * M_ + m0 + row];
        const float iv = inv[b * M_ + m0 + row];
        tile[row * 65 + c4 + 0] = __expf(v.x - mv) * iv;
        tile[row * 65 + c4 + 1] = __expf(v.y - mv) * iv;
        tile[row * 65 + c4 + 2] = __expf(v.z - mv) * iv;
        tile[row * 65 + c4 + 3] = __expf(v.w - mv) * iv;
    }
    __syncthreads();
    uint16_t* pb = pT + (size_t)b * N_ * M_;
#pragma unroll
    for (int q = 0; q < 2; ++q) {
        const int n = q * 32 + (t >> 3);
        const int mc = (t & 7) * 8;
        us8 o;
#pragma unroll
        for (int k = 0; k < 8; ++k) o[k] = f2b(tile[(mc + k) * 65 + n]);
        *(us8*)&pb[(size_t)(n0 + n) * M_ + m0 + mc] = o;
    }
}

// ---------------- transpose x: xt[b][d][m] = bf16(x[b][m][d]) ----------------
__global__ __launch_bounds__(256) void k_tx(const float* __restrict__ x,
                                            uint16_t* __restrict__ xt) {
    const int b = blockIdx.z, m0 = blockIdx.x * 64, d0 = blockIdx.y * 64;
    __shared__ float tile[64 * 65];
    const int t = threadIdx.x;
    const float* xb = x + (size_t)b * M_ * D_;
#pragma unroll
    for (int q = 0; q < 4; ++q) {
        const int row = q * 16 + (t >> 4);
        const int c4 = (t & 15) * 4;
        float4 v = *(const float4*)&xb[(size_t)(m0 + row) * D_ + d0 + c4];
        tile[row * 65 + c4 + 0] = v.x;
        tile[row * 65 + c4 + 1] = v.y;
        tile[row * 65 + c4 + 2] = v.z;
        tile[row * 65 + c4 + 3] = v.w;
    }
    __syncthreads();
    uint16_t* xtb = xt + (size_t)b * D_ * M_;
#pragma unroll
    for (int q = 0; q < 2; ++q) {
        const int d = q * 32 + (t >> 3);
        const int mc = (t & 7) * 8;
        us8 o;
#pragma unroll
        for (int k = 0; k < 8; ++k) o[k] = f2b(tile[(mc + k) * 65 + d]);
        *(us8*)&xtb[(size_t)(d0 + d) * M_ + m0 + mc] = o;
    }
}

// ---------------- GEMM2: out[b][n][d] = sum_m pT[b][n][m] * xt[b][d][m] ----------------
__global__ __launch_bounds__(256) void k_gemm2(const uint16_t* __restrict__ pT,
                                               const uint16_t* __restrict__ xt,
                                               float* __restrict__ out) {
    const int b = blockIdx.z;
    const int n0 = blockIdx.x * 128;
    const int d0 = blockIdx.y * 128;
    __shared__ __align__(16) uint16_t lds[8192];  // 2 tiles of 128x32 bf16

    const int tid = threadIdx.x;
    const int lane = tid & 63;
    const int wid = tid >> 6;
    const int wn = (wid & 1) * 64;
    const int wd = (wid >> 1) * 64;
    const int quad = lane >> 4;
    const int r16 = lane & 15;

    const uint16_t* srcA = pT + ((size_t)b * N_ + n0) * M_;
    const uint16_t* srcB = xt + ((size_t)b * D_ + d0) * M_;

    f32x4 acc[4][4];
#pragma unroll
    for (int i = 0; i < 4; ++i)
#pragma unroll
        for (int j = 0; j < 4; ++j) acc[i][j] = (f32x4){0.f, 0.f, 0.f, 0.f};

    for (int kt = 0; kt < M_ / 32; ++kt) {
#pragma unroll
        for (int c = 0; c < 4; ++c) {
            const int offbase = c * 2048 + wid * 512;
            const int tile = offbase >> 12;  // 0 -> A, 1 -> B
            const int o = (offbase & 4095) + lane * 8;
            const int row = o >> 5;
            const int kk = o & 31;
            const uint16_t* sp = tile ? srcB : srcA;
            gld16(sp + (size_t)row * M_ + kt * 32 + kk, &lds[offbase]);
        }
        __syncthreads();

        bf16x8 a[4], bb[4];
#pragma unroll
        for (int i = 0; i < 4; ++i) {
            a[i]  = *(const bf16x8*)&lds[(wn + i * 16 + r16) * 32 + quad * 8];
            bb[i] = *(const bf16x8*)&lds[4096 + (wd + i * 16 + r16) * 32 + quad * 8];
        }
#pragma unroll
        for (int i = 0; i < 4; ++i)
#pragma unroll
            for (int j = 0; j < 4; ++j)
                acc[i][j] = __builtin_amdgcn_mfma_f32_16x16x32_bf16(a[i], bb[j], acc[i][j], 0, 0, 0);
        __syncthreads();
    }

    float* ob = out + (size_t)b * N_ * D_;
#pragma unroll
    for (int i = 0; i < 4; ++i) {
        const int rbase = n0 + wn + i * 16 + quad * 4;
#pragma unroll
        for (int j = 0; j < 4; ++j) {
            const int col = d0 + wd + j * 16 + r16;
#pragma unroll
            for (int r = 0; r < 4; ++r)
                ob[(size_t)(rbase + r) * D_ + col] = acc[i][j][r];
        }
    }
}

extern "C" void kernel_launch(void* const* d_in, const int* in_sizes, int n_in,
                              void* d_out, int out_size, void* d_ws, size_t ws_size,
                              hipStream_t stream) {
    const float* x = (const float*)d_in[0];
    const float* y = (const float*)d_in[1];
    float* out = (float*)d_out;
    char* ws = (char*)d_ws;

    // Per-chunk footprint (g batches), with overlays: exactly 32g MiB.
    //   [xh 4g][xl 4g][yh 4g][yl 4g][e 16g]
    // After gemm1 the split region is dead:
    //   stats (mx,inv) overlay xh; xt overlays xl; pT overlays yh+yl.
    const size_t MiB = 1024 * 1024;
    int g = 8;
    while (g > 1 && (size_t)g * 32 * MiB > ws_size) g >>= 1;
    if ((size_t)g * 32 * MiB > ws_size) return;  // ws too small: clean fail (diagnostic)

    const size_t T = (size_t)g * M_ * D_ * 2;  // one split tensor (4g MiB)
    uint16_t* xh = (uint16_t*)(ws + 0 * T);
    uint16_t* xl = (uint16_t*)(ws + 1 * T);
    uint16_t* yh = (uint16_t*)(ws + 2 * T);
    uint16_t* yl = (uint16_t*)(ws + 3 * T);
    float*    e  = (float*)(ws + 4 * T);
    float*    mx = (float*)(ws);               // overlays xh (dead after gemm1)
    float*    inv = mx + (size_t)g * M_;
    uint16_t* xt = xl;                          // overlays xl (dead after gemm1)
    uint16_t* pT = yh;                          // overlays yh+yl (dead after gemm1)

    for (int c0 = 0; c0 < B_; c0 += g) {
        const float* xc = x + (size_t)c0 * M_ * D_;
        const float* yc = y + (size_t)c0 * N_ * D_;
        float* oc = out + (size_t)c0 * N_ * D_;

        hipLaunchKernelGGL(k_split, dim3((g * M_ * D_) / (256 * 4)), dim3(256), 0, stream,
                           xc, yc, xh, xl, yh, yl);
        hipLaunchKernelGGL(k_gemm1, dim3(M_ / 128, N_ / 128, g), dim3(256), 0, stream,
                           xh, xl, yh, yl, e);
        hipLaunchKernelGGL(k_rowstats, dim3(g * M_), dim3(256), 0, stream, e, mx, inv);
        hipLaunchKernelGGL(k_texp, dim3(M_ / 64, N_ / 64, g), dim3(256), 0, stream,
                           e, mx, inv, pT);
        hipLaunchKernelGGL(k_tx, dim3(M_ / 64, D_ / 64, g), dim3(256), 0, stream, xc, xt);
        hipLaunchKernelGGL(k_gemm2, dim3(N_ / 128, D_ / 128, g), dim3(256), 0, stream,
                           pT, xt, oc);
    }
}

// Round 5
// 524.195 us; speedup vs baseline: 1.0422x; 1.0422x over previous
//
#include <hip/hip_runtime.h>
#include <hip/hip_bf16.h>
#include <stdint.h>

#define B_ 8
#define M_ 2048
#define N_ 2048
#define D_ 1024

typedef __bf16 bf16x8 __attribute__((ext_vector_type(8)));
typedef float f32x4 __attribute__((ext_vector_type(4)));
typedef uint16_t us4 __attribute__((ext_vector_type(4)));
typedef uint16_t us8 __attribute__((ext_vector_type(8)));

__device__ __forceinline__ uint16_t f2b(float f) {
    uint32_t u = __float_as_uint(f);
    return (uint16_t)((u + 0x7FFFu + ((u >> 16) & 1u)) >> 16);
}
__device__ __forceinline__ float b2f(uint16_t h) {
    return __uint_as_float(((uint32_t)h) << 16);
}

__device__ __forceinline__ void gld16(const uint16_t* g, const uint16_t* l) {
    __builtin_amdgcn_global_load_lds(
        (const __attribute__((address_space(1))) uint32_t*)g,
        (__attribute__((address_space(3))) uint32_t*)l,
        16, 0, 0);
}

// ---------------- split x,y into bf16 hi/lo ----------------
__global__ __launch_bounds__(256) void k_split(const float* __restrict__ x,
                                               const float* __restrict__ y,
                                               uint16_t* __restrict__ xh, uint16_t* __restrict__ xl,
                                               uint16_t* __restrict__ yh, uint16_t* __restrict__ yl) {
    const int i = (blockIdx.x * 256 + threadIdx.x) * 4;
    float4 vx = *(const float4*)(x + i);
    float4 vy = *(const float4*)(y + i);
    float fx[4] = {vx.x, vx.y, vx.z, vx.w};
    float fy[4] = {vy.x, vy.y, vy.z, vy.w};
    us4 hx, lx, hy, ly;
#pragma unroll
    for (int k = 0; k < 4; ++k) {
        uint16_t h = f2b(fx[k]);
        hx[k] = h; lx[k] = f2b(fx[k] - b2f(h));
        uint16_t g = f2b(fy[k]);
        hy[k] = g; ly[k] = f2b(fy[k] - b2f(g));
    }
    *(us4*)(xh + i) = hx;
    *(us4*)(xl + i) = lx;
    *(us4*)(yh + i) = hy;
    *(us4*)(yl + i) = ly;
}

// ---------------- GEMM1: e[b][m][n] = xh.yh^T + xh.yl^T + xl.yh^T ----------------
// LDS granule swizzle (BK=32, 4x16B granules/row): data granule g of row r is
// stored at position g ^ ((r>>1)&3) -> fragment ds_read_b128 hits 8 distinct
// 4-bank groups per 8 lanes (2-way over 16 = conflict-free, m136).
__global__ __launch_bounds__(256) void k_gemm1(const uint16_t* __restrict__ xh,
                                               const uint16_t* __restrict__ xl,
                                               const uint16_t* __restrict__ yh,
                                               const uint16_t* __restrict__ yl,
                                               float* __restrict__ e) {
    const int b = blockIdx.z;
    const int m0 = blockIdx.x * 128;
    const int n0 = blockIdx.y * 128;
    __shared__ __align__(16) uint16_t lds[16384];  // 4 tiles of 128x32 bf16

    const int tid = threadIdx.x;
    const int lane = tid & 63;
    const int wid = tid >> 6;
    const int wm = (wid & 1) * 64;
    const int wn = (wid >> 1) * 64;
    const int quad = lane >> 4;
    const int r16 = lane & 15;
    const int swz = quad ^ ((r16 >> 1) & 3);  // (i*16 multiples don't affect (row>>1)&3)

    const uint16_t* src[4];
    src[0] = xh + ((size_t)b * M_ + m0) * D_;
    src[1] = xl + ((size_t)b * M_ + m0) * D_;
    src[2] = yh + ((size_t)b * N_ + n0) * D_;
    src[3] = yl + ((size_t)b * N_ + n0) * D_;

    f32x4 acc[4][4];
#pragma unroll
    for (int i = 0; i < 4; ++i)
#pragma unroll
        for (int j = 0; j < 4; ++j) acc[i][j] = (f32x4){0.f, 0.f, 0.f, 0.f};

    for (int kt = 0; kt < D_ / 32; ++kt) {
#pragma unroll
        for (int c = 0; c < 8; ++c) {
            const int offbase = c * 2048 + wid * 512;   // wave-uniform LDS dest
            const int tile = offbase >> 12;
            const int o = (offbase & 4095) + lane * 8;  // element position in tile
            const int row = o >> 5;
            const int gp = (o & 31) >> 3;               // granule position 0..3
            const int gd = gp ^ ((row >> 1) & 3);       // data granule (swizzle)
            gld16(src[tile] + (size_t)row * D_ + kt * 32 + gd * 8, &lds[offbase]);
        }
        __syncthreads();

        bf16x8 ah[4], al[4], bh[4], bl[4];
#pragma unroll
        for (int i = 0; i < 4; ++i) {
            const int ra = (wm + i * 16 + r16) * 32 + swz * 8;
            ah[i] = *(const bf16x8*)&lds[ra];
            al[i] = *(const bf16x8*)&lds[4096 + ra];
            const int rb = (wn + i * 16 + r16) * 32 + swz * 8;
            bh[i] = *(const bf16x8*)&lds[8192 + rb];
            bl[i] = *(const bf16x8*)&lds[12288 + rb];
        }
#pragma unroll
        for (int i = 0; i < 4; ++i)
#pragma unroll
            for (int j = 0; j < 4; ++j) {
                acc[i][j] = __builtin_amdgcn_mfma_f32_16x16x32_bf16(ah[i], bh[j], acc[i][j], 0, 0, 0);
                acc[i][j] = __builtin_amdgcn_mfma_f32_16x16x32_bf16(ah[i], bl[j], acc[i][j], 0, 0, 0);
                acc[i][j] = __builtin_amdgcn_mfma_f32_16x16x32_bf16(al[i], bh[j], acc[i][j], 0, 0, 0);
            }
        __syncthreads();
    }

    float* eb = e + (size_t)b * M_ * N_;
#pragma unroll
    for (int i = 0; i < 4; ++i) {
        const int rbase = m0 + wm + i * 16 + quad * 4;
#pragma unroll
        for (int j = 0; j < 4; ++j) {
            const int col = n0 + wn + j * 16 + r16;
#pragma unroll
            for (int r = 0; r < 4; ++r)
                eb[(size_t)(rbase + r) * N_ + col] = acc[i][j][r];
        }
    }
}

// ---------------- row stats: max and 1/sum(exp) per (b,m) ----------------
__global__ __launch_bounds__(256) void k_rowstats(const float* __restrict__ e,
                                                  float* __restrict__ mx,
                                                  float* __restrict__ inv) {
    const int row = blockIdx.x;  // b_local*M + m
    const float* p = e + (size_t)row * N_;
    const int t = threadIdx.x;
    float4 v0 = ((const float4*)p)[t];
    float4 v1 = ((const float4*)p)[t + 256];
    float m = fmaxf(fmaxf(fmaxf(v0.x, v0.y), fmaxf(v0.z, v0.w)),
                    fmaxf(fmaxf(v1.x, v1.y), fmaxf(v1.z, v1.w)));
#pragma unroll
    for (int s = 32; s > 0; s >>= 1) m = fmaxf(m, __shfl_xor(m, s, 64));
    __shared__ float smax[4];
    __shared__ float ssum[4];
    const int wid = t >> 6, lane = t & 63;
    if (lane == 0) smax[wid] = m;
    __syncthreads();
    m = fmaxf(fmaxf(smax[0], smax[1]), fmaxf(smax[2], smax[3]));
    float s = __expf(v0.x - m) + __expf(v0.y - m) + __expf(v0.z - m) + __expf(v0.w - m)
            + __expf(v1.x - m) + __expf(v1.y - m) + __expf(v1.z - m) + __expf(v1.w - m);
#pragma unroll
    for (int sh = 32; sh > 0; sh >>= 1) s += __shfl_xor(s, sh, 64);
    if (lane == 0) ssum[wid] = s;
    __syncthreads();
    if (t == 0) {
        mx[row] = m;
        inv[row] = 1.0f / (ssum[0] + ssum[1] + ssum[2] + ssum[3]);
    }
}

// ---------------- transposed softmax: pT[b][n][m] = bf16(exp(e[b][m][n]-mx)*inv) ----------------
__global__ __launch_bounds__(256) void k_texp(const float* __restrict__ e,
                                              const float* __restrict__ mx,
                                              const float* __restrict__ inv,
                                              uint16_t* __restrict__ pT) {
    const int b = blockIdx.z, m0 = blockIdx.x * 64, n0 = blockIdx.y * 64;
    __shared__ float tile[64 * 65];
    const int t = threadIdx.x;
    const float* eb = e + (size_t)b * M_ * N_;
#pragma unroll
    for (int q = 0; q < 4; ++q) {
        const int row = q * 16 + (t >> 4);
        const int c4 = (t & 15) * 4;
        float4 v = *(const float4*)&eb[(size_t)(m0 + row) * N_ + n0 + c4];
        const float mv = mx[b * M_ + m0 + row];
        const float iv = inv[b * M_ + m0 + row];
        tile[row * 65 + c4 + 0] = __expf(v.x - mv) * iv;
        tile[row * 65 + c4 + 1] = __expf(v.y - mv) * iv;
        tile[row * 65 + c4 + 2] = __expf(v.z - mv) * iv;
        tile[row * 65 + c4 + 3] = __expf(v.w - mv) * iv;
    }
    __syncthreads();
    uint16_t* pb = pT + (size_t)b * N_ * M_;
#pragma unroll
    for (int q = 0; q < 2; ++q) {
        const int n = q * 32 + (t >> 3);
        const int mc = (t & 7) * 8;
        us8 o;
#pragma unroll
        for (int k = 0; k < 8; ++k) o[k] = f2b(tile[(mc + k) * 65 + n]);
        *(us8*)&pb[(size_t)(n0 + n) * M_ + m0 + mc] = o;
    }
}

// ---------------- transpose x: xt[b][d][m] = bf16(x[b][m][d]) ----------------
__global__ __launch_bounds__(256) void k_tx(const float* __restrict__ x,
                                            uint16_t* __restrict__ xt) {
    const int b = blockIdx.z, m0 = blockIdx.x * 64, d0 = blockIdx.y * 64;
    __shared__ float tile[64 * 65];
    const int t = threadIdx.x;
    const float* xb = x + (size_t)b * M_ * D_;
#pragma unroll
    for (int q = 0; q < 4; ++q) {
        const int row = q * 16 + (t >> 4);
        const int c4 = (t & 15) * 4;
        float4 v = *(const float4*)&xb[(size_t)(m0 + row) * D_ + d0 + c4];
        tile[row * 65 + c4 + 0] = v.x;
        tile[row * 65 + c4 + 1] = v.y;
        tile[row * 65 + c4 + 2] = v.z;
        tile[row * 65 + c4 + 3] = v.w;
    }
    __syncthreads();
    uint16_t* xtb = xt + (size_t)b * D_ * M_;
#pragma unroll
    for (int q = 0; q < 2; ++q) {
        const int d = q * 32 + (t >> 3);
        const int mc = (t & 7) * 8;
        us8 o;
#pragma unroll
        for (int k = 0; k < 8; ++k) o[k] = f2b(tile[(mc + k) * 65 + d]);
        *(us8*)&xtb[(size_t)(d0 + d) * M_ + m0 + mc] = o;
    }
}

// ---------------- GEMM2: out[b][n][d] = sum_m pT[b][n][m] * xt[b][d][m] ----------------
// BK=64 (row = 128B = 32 dwords, bank-degenerate unswizzled): data granule g of
// row r stored at position g ^ (r&7) -> 8 lanes cover all 32 banks, free.
__global__ __launch_bounds__(256) void k_gemm2(const uint16_t* __restrict__ pT,
                                               const uint16_t* __restrict__ xt,
                                               float* __restrict__ out) {
    const int b = blockIdx.z;
    const int n0 = blockIdx.x * 128;
    const int d0 = blockIdx.y * 128;
    __shared__ __align__(16) uint16_t lds[16384];  // 2 tiles of 128x64 bf16

    const int tid = threadIdx.x;
    const int lane = tid & 63;
    const int wid = tid >> 6;
    const int wn = (wid & 1) * 64;
    const int wd = (wid >> 1) * 64;
    const int quad = lane >> 4;
    const int r16 = lane & 15;

    const uint16_t* srcA = pT + ((size_t)b * N_ + n0) * M_;
    const uint16_t* srcB = xt + ((size_t)b * D_ + d0) * M_;

    f32x4 acc[4][4];
#pragma unroll
    for (int i = 0; i < 4; ++i)
#pragma unroll
        for (int j = 0; j < 4; ++j) acc[i][j] = (f32x4){0.f, 0.f, 0.f, 0.f};

    for (int kt = 0; kt < M_ / 64; ++kt) {
#pragma unroll
        for (int c = 0; c < 8; ++c) {
            const int offbase = c * 2048 + wid * 512;
            const int tile = offbase >> 13;             // 8192 elems per tile
            const int o = (offbase & 8191) + lane * 8;
            const int row = o >> 6;                     // 64 elems per row
            const int gp = (o & 63) >> 3;               // granule position 0..7
            const int gd = gp ^ (row & 7);              // data granule (swizzle)
            const uint16_t* sp = tile ? srcB : srcA;
            gld16(sp + (size_t)row * M_ + kt * 64 + gd * 8, &lds[offbase]);
        }
        __syncthreads();

#pragma unroll
        for (int h = 0; h < 2; ++h) {                   // two K=32 halves
            const int p = (h * 4 + quad) ^ (r16 & 7);   // swizzled granule pos
            bf16x8 a[4], bb[4];
#pragma unroll
            for (int i = 0; i < 4; ++i) {
                a[i]  = *(const bf16x8*)&lds[(wn + i * 16 + r16) * 64 + p * 8];
                bb[i] = *(const bf16x8*)&lds[8192 + (wd + i * 16 + r16) * 64 + p * 8];
            }
#pragma unroll
            for (int i = 0; i < 4; ++i)
#pragma unroll
                for (int j = 0; j < 4; ++j)
                    acc[i][j] = __builtin_amdgcn_mfma_f32_16x16x32_bf16(a[i], bb[j], acc[i][j], 0, 0, 0);
        }
        __syncthreads();
    }

    float* ob = out + (size_t)b * N_ * D_;
#pragma unroll
    for (int i = 0; i < 4; ++i) {
        const int rbase = n0 + wn + i * 16 + quad * 4;
#pragma unroll
        for (int j = 0; j < 4; ++j) {
            const int col = d0 + wd + j * 16 + r16;
#pragma unroll
            for (int r = 0; r < 4; ++r)
                ob[(size_t)(rbase + r) * D_ + col] = acc[i][j][r];
        }
    }
}

extern "C" void kernel_launch(void* const* d_in, const int* in_sizes, int n_in,
                              void* d_out, int out_size, void* d_ws, size_t ws_size,
                              hipStream_t stream) {
    const float* x = (const float*)d_in[0];
    const float* y = (const float*)d_in[1];
    float* out = (float*)d_out;
    char* ws = (char*)d_ws;

    // Per-chunk footprint (g batches), with overlays: exactly 32g MiB.
    //   [xh 4g][xl 4g][yh 4g][yl 4g][e 16g]
    // After gemm1 the split region is dead:
    //   stats (mx,inv) overlay xh; xt overlays xl; pT overlays yh+yl.
    const size_t MiB = 1024 * 1024;
    int g = 8;
    while (g > 1 && (size_t)g * 32 * MiB > ws_size) g >>= 1;
    if ((size_t)g * 32 * MiB > ws_size) return;  // ws too small: clean fail (diagnostic)

    const size_t T = (size_t)g * M_ * D_ * 2;  // one split tensor (4g MiB)
    uint16_t* xh = (uint16_t*)(ws + 0 * T);
    uint16_t* xl = (uint16_t*)(ws + 1 * T);
    uint16_t* yh = (uint16_t*)(ws + 2 * T);
    uint16_t* yl = (uint16_t*)(ws + 3 * T);
    float*    e  = (float*)(ws + 4 * T);
    float*    mx = (float*)(ws);               // overlays xh (dead after gemm1)
    float*    inv = mx + (size_t)g * M_;
    uint16_t* xt = xl;                          // overlays xl (dead after gemm1)
    uint16_t* pT = yh;                          // overlays yh+yl (dead after gemm1)

    for (int c0 = 0; c0 < B_; c0 += g) {
        const float* xc = x + (size_t)c0 * M_ * D_;
        const float* yc = y + (size_t)c0 * N_ * D_;
        float* oc = out + (size_t)c0 * N_ * D_;

        hipLaunchKernelGGL(k_split, dim3((g * M_ * D_) / (256 * 4)), dim3(256), 0, stream,
                           xc, yc, xh, xl, yh, yl);
        hipLaunchKernelGGL(k_gemm1, dim3(M_ / 128, N_ / 128, g), dim3(256), 0, stream,
                           xh, xl, yh, yl, e);
        hipLaunchKernelGGL(k_rowstats, dim3(g * M_), dim3(256), 0, stream, e, mx, inv);
        hipLaunchKernelGGL(k_texp, dim3(M_ / 64, N_ / 64, g), dim3(256), 0, stream,
                           e, mx, inv, pT);
        hipLaunchKernelGGL(k_tx, dim3(M_ / 64, D_ / 64, g), dim3(256), 0, stream, xc, xt);
        hipLaunchKernelGGL(k_gemm2, dim3(N_ / 128, D_ / 128, g), dim3(256), 0, stream,
                           pT, xt, oc);
    }
}